// Round 9
// baseline (519.397 us; speedup 1.0000x reference)
//
#include <hip/hip_runtime.h>
#include <stdint.h>

#define N_NODES   120000
#define EM        128
#define N_EDGES_C 1920000
#define BSZ       1024
#define SL        10
#define N_GATHER  (BSZ*SL + BSZ)        // 11264
#define N_OUTCOL  (N_NODES - 1)         // 119999
#define NBLK_E    1875                  // 1875 * 1024 = 1920000 exactly
#define CHUNK_E   1024
#define NPANEL4   235                   // panels of 512 cols: 235*512 = 120320 >= 120000
#define NBLK_S4   (NPANEL4*8)           // 1880 = 8*235

typedef __attribute__((ext_vector_type(8))) short bf16x8;
typedef __attribute__((ext_vector_type(4))) float f32x4;

#define GLOBAL_AS __attribute__((address_space(1)))
#define LDS_AS    __attribute__((address_space(3)))

__device__ inline void gload_lds16(const void* g, void* l) {
  __builtin_amdgcn_global_load_lds((const GLOBAL_AS unsigned int*)g,
                                   (LDS_AS unsigned int*)l, 16, 0, 0);
}

__device__ inline unsigned pk_bf16(float a, float b) {
  unsigned ua = __builtin_bit_cast(unsigned, a);
  ua += 0x7fffu + ((ua >> 16) & 1u);
  unsigned ub = __builtin_bit_cast(unsigned, b);
  ub += 0x7fffu + ((ub >> 16) & 1u);
  return (ua >> 16) | (ub & 0xffff0000u);
}

__device__ inline float bf2f(unsigned short u) {
  return __builtin_bit_cast(float, ((unsigned)u) << 16);
}

// ---- workspace layout (bytes) ----
#define MAP_OFF   0u          // int[120000]  node -> slot (-1 = unused)
#define CNT_OFF   480000u     // int[2]: slotCount (+pad to DEG_OFF)
#define DEG_OFF   480256u     // int[11264]
#define OFFS_OFF  525312u     // int[11264]
#define CUR_OFF   570368u     // int[11264]
#define AGG_OFF   615424u     // float[11264*128]
#define SORT_OFF  21742592u   // int[N_EDGES]
#define NE_OFF    29422592u   // float[10240*128] node_embeds
#define UE_OFF    34665472u   // float[1024*128]  user_embeds
#define SB_OFF    35189760u   // ushort[1024*128] seq_emb bf16 (256 KB)
#define V2EB_OFF  37748736u   // ushort[120000*128] v2e bf16 (30.72 MB)

// ---------------- init: map=-1, counters+deg=0, one dispatch ----------------
__global__ __launch_bounds__(256) void k_init(int* __restrict__ ws_ints) {
  int t = blockIdx.x*256 + threadIdx.x;          // grid 513*256 = 131328 = 525312/4
  ws_ints[t] = (t < N_NODES) ? -1 : 0;
}

// ---------------- v2e f32 -> bf16 pre-pass ----------------
__global__ __launch_bounds__(256) void k_tobf16(const float* __restrict__ v2e,
    unsigned short* __restrict__ v2eb) {
  size_t base = ((size_t)blockIdx.x*256 + threadIdx.x) * 8;   // grid covers exactly
  float4 v0 = *(const float4*)(v2e + base);
  float4 v1 = *(const float4*)(v2e + base + 4);
  uint4 o;
  o.x = pk_bf16(v0.x, v0.y); o.y = pk_bf16(v0.z, v0.w);
  o.z = pk_bf16(v1.x, v1.y); o.w = pk_bf16(v1.z, v1.w);
  *(uint4*)(v2eb + base) = o;
}

// ---------------- slot assignment for gathered nodes ----------------
__global__ __launch_bounds__(256) void k_assign(const int* __restrict__ seq,
    const int* __restrict__ user, const int* __restrict__ item_num,
    int* __restrict__ map, int* __restrict__ slotCount) {
  int t = blockIdx.x*256 + threadIdx.x;
  int idx = (t < BSZ*SL) ? seq[t] : (user[t - BSZ*SL] + item_num[0]);
  int old = atomicCAS(map + idx, -1, -2);
  if (old == -1) {
    int slot = atomicAdd(slotCount, 1);
    atomicExch(map + idx, slot);
  }
}

// ---------------- pass 1: per-slot degree (spread atomics only) ----------------
__global__ __launch_bounds__(256) void k_count(const int* __restrict__ dst,
    const int* __restrict__ map, int* __restrict__ deg_i) {
  int beg = blockIdx.x * CHUNK_E;
  #pragma unroll
  for (int it = 0; it < CHUNK_E/256; ++it) {
    int e = beg + it*256 + threadIdx.x;
    int slot = map[dst[e]];
    if (slot >= 0) atomicAdd(deg_i + slot, 1);
  }
}

// ---------------- exclusive scan of per-slot degrees ----------------
__global__ __launch_bounds__(256) void k_scan(const int* __restrict__ deg_i,
    int* __restrict__ offs, int* __restrict__ cursor) {
  __shared__ int wsum[4];
  int tid = threadIdx.x;
  int lane = tid & 63, wv = tid >> 6;
  int carry = 0;
  for (int c = 0; c < N_GATHER/256; ++c) {
    int i = c*256 + tid;
    int v = deg_i[i];
    int s = v;
    #pragma unroll
    for (int o = 1; o < 64; o <<= 1) {
      int t = __shfl_up(s, o);
      if (lane >= o) s += t;
    }
    if (lane == 63) wsum[wv] = s;
    __syncthreads();
    int wbase = 0;
    #pragma unroll
    for (int q = 0; q < 4; ++q) if (q < wv) wbase += wsum[q];
    int tot = wsum[0] + wsum[1] + wsum[2] + wsum[3];
    int excl = s - v + wbase + carry;
    offs[i] = excl;
    cursor[i] = excl;
    carry += tot;
    __syncthreads();
  }
}

// ---------------- pass 2: direct scatter into per-slot buckets ----------------
__global__ __launch_bounds__(256) void k_place(const int* __restrict__ src,
    const int* __restrict__ dst, const int* __restrict__ map,
    int* __restrict__ cursor, int* __restrict__ sorted) {
  int beg = blockIdx.x * CHUNK_E;
  #pragma unroll
  for (int it = 0; it < CHUNK_E/256; ++it) {
    int e = beg + it*256 + threadIdx.x;
    int slot = map[dst[e]];
    if (slot >= 0) {
      int pos = atomicAdd(cursor + slot, 1);
      sorted[pos] = src[e];
    }
  }
}

// ---------------- per-slot neighbor sum, bf16 gather, f32 accum ----------------
__global__ __launch_bounds__(256) void k_reduce(const unsigned short* __restrict__ v2eb,
    const int* __restrict__ offs, const int* __restrict__ deg_i,
    const int* __restrict__ slotCount, const int* __restrict__ sorted,
    float* __restrict__ agg) {
  int nslots = slotCount[0];
  int g = (blockIdx.x*blockDim.x + threadIdx.x) >> 5;
  int lg = threadIdx.x & 31;
  int ngrp = (gridDim.x*blockDim.x) >> 5;
  for (int slot = g; slot < nslots; slot += ngrp) {
    int beg = offs[slot];
    int end = beg + deg_i[slot];
    float a0 = 0.f, a1 = 0.f, a2 = 0.f, a3 = 0.f;
    for (int e = beg; e < end; ++e) {
      int s = sorted[e];
      ushort4 v = *(const ushort4*)(v2eb + (size_t)s*EM + lg*4);
      a0 += bf2f(v.x); a1 += bf2f(v.y); a2 += bf2f(v.z); a3 += bf2f(v.w);
    }
    *(float4*)(agg + (size_t)slot*EM + lg*4) = make_float4(a0, a1, a2, a3);
  }
}

// ---------------- SAGE layer + gather, only for needed rows ----------------
__global__ __launch_bounds__(128) void k_embed(const int* __restrict__ seq,
    const int* __restrict__ user, const int* __restrict__ item_num,
    const int* __restrict__ map, const int* __restrict__ deg_i,
    const float* __restrict__ agg, const float* __restrict__ v2e,
    const float* __restrict__ W_self, const float* __restrict__ W_neigh,
    const float* __restrict__ sage_b,
    float* __restrict__ node_emb, float* __restrict__ user_emb) {
  __shared__ float xs[8][EM];
  __shared__ float xa[8][EM];
  int j = threadIdx.x;
  int base = blockIdx.x * 8;
  #pragma unroll
  for (int r = 0; r < 8; ++r) {
    int rg = base + r;
    int idx = (rg < BSZ*SL) ? seq[rg] : (user[rg - BSZ*SL] + item_num[0]);
    int slot = map[idx];
    float rd = 1.0f / fmaxf((float)deg_i[slot], 1.0f);
    xs[r][j] = v2e[(size_t)idx*EM + j];
    xa[r][j] = agg[(size_t)slot*EM + j] * rd;
  }
  __syncthreads();
  float acc[8] = {0.f,0.f,0.f,0.f,0.f,0.f,0.f,0.f};
  for (int k = 0; k < EM; ++k) {
    float a  = W_self[k*EM + j];
    float bb = W_neigh[k*EM + j];
    #pragma unroll
    for (int r = 0; r < 8; ++r) acc[r] += xs[r][k]*a + xa[r][k]*bb;
  }
  float bias = sage_b[j];
  #pragma unroll
  for (int r = 0; r < 8; ++r) {
    int rg = base + r;
    float h = fmaxf(acc[r] + bias, 0.0f);
    float emb = 0.5f * (h + xs[r][j]);
    if (rg < BSZ*SL) node_emb[(size_t)rg*EM + j] = emb;
    else             user_emb[(size_t)(rg - BSZ*SL)*EM + j] = emb;
  }
}

// ---------------- session attention (one block per batch row) ----------------
__global__ __launch_bounds__(128) void k_session(
    const float* __restrict__ node_emb, const float* __restrict__ user_emb,
    const int* __restrict__ pos_idx, const float* __restrict__ mask_in,
    const float* __restrict__ pos_emb,
    const float* __restrict__ w1, const float* __restrict__ w2,
    const float* __restrict__ glu1_w, const float* __restrict__ glu1_b,
    const float* __restrict__ glu2_w,
    const float* __restrict__ w3, const float* __restrict__ w4,
    const float* __restrict__ glu3_w, const float* __restrict__ glu3_b,
    const float* __restrict__ glu4_w,
    const float* __restrict__ sc_w, const float* __restrict__ sc_b,
    unsigned short* __restrict__ seqb) {
  __shared__ float ne[SL][EM], pe[SL][EM], r1[SL][EM], r2[SL][EM];
  __shared__ float ue[EM], hsS[EM], redA[EM];
  __shared__ float mls[SL], bl1[SL], bl2[SL];
  __shared__ float alphaS;
  int b = blockIdx.x, j = threadIdx.x;
  ue[j] = user_emb[b*EM + j];
  if (j < SL) mls[j] = mask_in[b*SL + j];
  #pragma unroll
  for (int l = 0; l < SL; ++l) {
    ne[l][j] = node_emb[(size_t)(b*SL + l)*EM + j];
    int p = pos_idx[b*SL + l];
    pe[l][j] = pos_emb[(size_t)p*EM + j];
  }
  __syncthreads();
  float s = 0.f, ms = 0.f;
  #pragma unroll
  for (int l = 0; l < SL; ++l) { s += mls[l]*ne[l][j]; ms += mls[l]; }
  hsS[j] = s / ms;
  float a1[SL], a2[SL];
  #pragma unroll
  for (int l = 0; l < SL; ++l) { a1[l] = 0.f; a2[l] = 0.f; }
  for (int k = 0; k < EM; ++k) {
    float wt  = w1[k*EM + j];
    float wb  = w1[(k+EM)*EM + j];
    float w3v = w3[k*EM + j];
    #pragma unroll
    for (int l = 0; l < SL; ++l) {
      a1[l] += pe[l][k]*wt + ne[l][k]*wb;
      a2[l] += ne[l][k]*w3v;
    }
  }
  #pragma unroll
  for (int l = 0; l < SL; ++l) { r1[l][j] = tanhf(a1[l]); r2[l][j] = tanhf(a2[l]); }
  __syncthreads();
  float g1[SL], g2[SL];
  #pragma unroll
  for (int l = 0; l < SL; ++l) { g1[l] = 0.f; g2[l] = 0.f; }
  float hsa = 0.f, uea = 0.f;
  for (int k = 0; k < EM; ++k) {
    float c1 = glu1_w[k*EM + j];
    float c2 = glu2_w[k*EM + j];
    float c3 = glu3_w[k*EM + j];
    float c4 = glu4_w[k*EM + j];
    hsa += hsS[k]*c2;
    uea += ue[k]*c4;
    #pragma unroll
    for (int l = 0; l < SL; ++l) {
      g1[l] += r1[l][k]*c1;
      g2[l] += r2[l][k]*c3;
    }
  }
  float b1 = glu1_b[j], b3 = glu3_b[j];
  float w2v = w2[j], w4v = w4[j];
  __syncthreads();
  #pragma unroll
  for (int l = 0; l < SL; ++l) {
    float s1 = 1.f/(1.f + expf(-(g1[l] + b1 + hsa)));
    float s2 = 1.f/(1.f + expf(-(g2[l] + b3 + uea)));
    r1[l][j] = s1 * w2v;
    r2[l][j] = s2 * w4v;
  }
  __syncthreads();
  if (j < SL) {
    float t1 = 0.f, t2 = 0.f;
    for (int t = 0; t < EM; ++t) { t1 += r1[j][t]; t2 += r2[j][t]; }
    bl1[j] = t1 * mls[j];
    bl2[j] = t2 * mls[j];
  }
  __syncthreads();
  float sv = 0.f, su = 0.f;
  #pragma unroll
  for (int l = 0; l < SL; ++l) { sv += bl1[l]*ne[l][j]; su += bl2[l]*ne[l][j]; }
  redA[j] = sv*sc_w[j] + su*sc_w[EM + j];
  __syncthreads();
  if (j == 0) {
    float t = 0.f;
    for (int k = 0; k < EM; ++k) t += redA[k];
    alphaS = 1.f/(1.f + expf(-(t + sc_b[0])));
  }
  __syncthreads();
  float al = alphaS;
  float val = ue[j] + al*sv + (1.f - al)*su;
  unsigned uv = __builtin_bit_cast(unsigned, val);
  uv += 0x7fffu + ((uv >> 16) & 1u);
  seqb[b*EM + j] = (unsigned short)(uv >> 16);
}

// ---------------- scores: 128 rows x 512 cols per block, 4 pipelined tiles ----
// Same staging (pre-swizzled global_load_lds) and store pattern (r5 transpose +
// float4, measured WRITE=490MB) but 4 tiles/block: stores(t) overlap stage(t+1).
__global__ __launch_bounds__(256, 3) void k_scores(
    const unsigned short* __restrict__ seqb,
    const unsigned short* __restrict__ v2eb, float* __restrict__ out) {
  __shared__ char Bs[32768];
  __shared__ float scr[4][16][68];     // per-wave transpose scratch (padded +4)
  int tid = threadIdx.x;
  int bid = blockIdx.x;
  // bijective XCD swizzle (1880 = 8*235): consecutive lids share an XCD
  int lid = (bid & 7) * NPANEL4 + (bid >> 3);
  int m0 = (lid & 7) * 128;            // 8 m-blocks cycle within an XCD's chunk
  int p4 = lid >> 3;                   // 512-col panel index (0..234)
  int w = tid >> 6, lane = tid & 63;
  int wm = w >> 1, wn = w & 1;
  int lr = lane & 15, lg = lane >> 4;
  const char* v2eb_c = (const char*)v2eb;

  // per-lane staging geometry (constant across tiles)
  int srow[8], scol[8], schunk[8];
  #pragma unroll
  for (int i = 0; i < 8; ++i) {
    int chunk = i*4 + w;
    int o = chunk*1024 + lane*16;
    srow[i] = o >> 8;
    scol[i] = (o & 255) ^ ((srow[i] & 7) << 4);
    schunk[i] = chunk;
  }

  // stage tile 0
  {
    int nb = p4*512 + 0*128;
    #pragma unroll
    for (int i = 0; i < 8; ++i) {
      int rowg = nb + 1 + srow[i];
      if (rowg > N_OUTCOL) rowg = N_OUTCOL;
      gload_lds16(v2eb_c + (size_t)rowg*256 + scol[i], Bs + schunk[i]*1024);
    }
  }
  asm volatile("s_waitcnt vmcnt(0)");
  __syncthreads();

  float (*sw)[68] = scr[w];
  #pragma unroll 1
  for (int t = 0; t < 4; ++t) {
    int n0 = p4*512 + t*128;
    // ---- MFMA phase ----
    f32x4 acc[4][4];
    #pragma unroll
    for (int mi = 0; mi < 4; ++mi)
      #pragma unroll
      for (int ni = 0; ni < 4; ++ni)
        acc[mi][ni] = 0.f;
    #pragma unroll
    for (int ks = 0; ks < 4; ++ks) {
      bf16x8 a[4], bfr[4];
      #pragma unroll
      for (int mi = 0; mi < 4; ++mi)
        a[mi] = *(const bf16x8*)(seqb + (size_t)(m0 + wm*64 + mi*16 + lr)*EM + ks*32 + lg*8);
      #pragma unroll
      for (int ni = 0; ni < 4; ++ni) {
        int row = wn*64 + ni*16 + lr;
        int off = (row*256 + ks*64 + lg*16) ^ ((row & 7) << 4);
        bfr[ni] = *(const bf16x8*)(Bs + off);
      }
      #pragma unroll
      for (int mi = 0; mi < 4; ++mi)
        #pragma unroll
        for (int ni = 0; ni < 4; ++ni)
          acc[mi][ni] = __builtin_amdgcn_mfma_f32_16x16x32_bf16(a[mi], bfr[ni], acc[mi][ni], 0, 0, 0);
    }
    __syncthreads();                     // all waves done reading Bs
    // ---- issue next tile's staging (async; overlaps the store epilogue) ----
    if (t < 3) {
      int nb = p4*512 + (t+1)*128;
      #pragma unroll
      for (int i = 0; i < 8; ++i) {
        int rowg = nb + 1 + srow[i];
        if (rowg > N_OUTCOL) rowg = N_OUTCOL;
        gload_lds16(v2eb_c + (size_t)rowg*256 + scol[i], Bs + schunk[i]*1024);
      }
    }
    // ---- transpose epilogue: 4 chunks of 16 rows x 64 cols per wave ----
    int nbase = n0 + wn*64;
    #pragma unroll
    for (int mi = 0; mi < 4; ++mi) {
      #pragma unroll
      for (int ni = 0; ni < 4; ++ni)
        #pragma unroll
        for (int r = 0; r < 4; ++r)
          sw[lg*4 + r][ni*16 + lr] = acc[mi][ni][r];
      asm volatile("s_waitcnt lgkmcnt(0)" ::: "memory");
      #pragma unroll
      for (int q = 0; q < 4; ++q) {
        int row16 = q*4 + lg;
        float4 v = *(const float4*)&sw[row16][lr*4];
        int m = m0 + wm*64 + mi*16 + row16;
        int nc = nbase + lr*4;
        size_t base = (size_t)m * N_OUTCOL + nc;
        if (nc + 3 < N_OUTCOL) {
          *(float4*)(out + base) = v;
        } else if (nc < N_OUTCOL) {
          float vv[4] = {v.x, v.y, v.z, v.w};
          #pragma unroll
          for (int tt = 0; tt < 4; ++tt)
            if (nc + tt < N_OUTCOL) out[base + tt] = vv[tt];
        }
      }
      asm volatile("s_waitcnt lgkmcnt(0)" ::: "memory");
    }
    if (t < 3) {
      asm volatile("s_waitcnt vmcnt(0)");
      __syncthreads();                   // next tile's Bs ready
    }
  }
}

extern "C" void kernel_launch(void* const* d_in, const int* in_sizes, int n_in,
                              void* d_out, int out_size, void* d_ws, size_t ws_size,
                              hipStream_t stream) {
  const int*   src      = (const int*)d_in[0];
  const int*   dst      = (const int*)d_in[1];
  const int*   user     = (const int*)d_in[2];
  const int*   seq      = (const int*)d_in[3];
  const float* mask     = (const float*)d_in[4];
  const int*   pos_idx  = (const int*)d_in[6];
  const int*   item_num = (const int*)d_in[7];
  const float* v2e      = (const float*)d_in[8];
  const float* W_self   = (const float*)d_in[9];
  const float* W_neigh  = (const float*)d_in[10];
  const float* sage_b   = (const float*)d_in[11];
  const float* pos_emb  = (const float*)d_in[12];
  const float* w1       = (const float*)d_in[13];
  const float* w2       = (const float*)d_in[14];
  const float* glu1_w   = (const float*)d_in[15];
  const float* glu1_b   = (const float*)d_in[16];
  const float* glu2_w   = (const float*)d_in[17];
  const float* w3       = (const float*)d_in[18];
  const float* w4       = (const float*)d_in[19];
  const float* glu3_w   = (const float*)d_in[20];
  const float* glu3_b   = (const float*)d_in[21];
  const float* glu4_w   = (const float*)d_in[22];
  const float* sc_w     = (const float*)d_in[23];
  const float* sc_b     = (const float*)d_in[24];
  float* out = (float*)d_out;
  char*  ws  = (char*)d_ws;

  int*   map       = (int*)(ws + MAP_OFF);
  int*   slotCount = (int*)(ws + CNT_OFF);
  int*   deg_i     = (int*)(ws + DEG_OFF);
  int*   offs      = (int*)(ws + OFFS_OFF);
  int*   cursor    = (int*)(ws + CUR_OFF);
  float* agg       = (float*)(ws + AGG_OFF);
  int*   sorted    = (int*)(ws + SORT_OFF);
  float* node_emb  = (float*)(ws + NE_OFF);
  float* user_emb  = (float*)(ws + UE_OFF);
  unsigned short* seqb  = (unsigned short*)(ws + SB_OFF);
  unsigned short* v2eb  = (unsigned short*)(ws + V2EB_OFF);

  k_init<<<513, 256, 0, stream>>>((int*)ws);          // map=-1, counters+deg=0
  k_tobf16<<<7500, 256, 0, stream>>>(v2e, v2eb);      // 15.36M elems / 8
  k_assign<<<N_GATHER/256, 256, 0, stream>>>(seq, user, item_num, map, slotCount);
  k_count<<<NBLK_E, 256, 0, stream>>>(dst, map, deg_i);
  k_scan<<<1, 256, 0, stream>>>(deg_i, offs, cursor);
  k_place<<<NBLK_E, 256, 0, stream>>>(src, dst, map, cursor, sorted);
  k_reduce<<<1408, 256, 0, stream>>>(v2eb, offs, deg_i, slotCount, sorted, agg);
  k_embed<<<N_GATHER/8, 128, 0, stream>>>(seq, user, item_num, map, deg_i, agg, v2e,
                                          W_self, W_neigh, sage_b, node_emb, user_emb);
  k_session<<<BSZ, 128, 0, stream>>>(node_emb, user_emb, pos_idx, mask, pos_emb,
      w1, w2, glu1_w, glu1_b, glu2_w, w3, w4, glu3_w, glu3_b, glu4_w, sc_w, sc_b, seqb);
  k_scores<<<NBLK_S4, 256, 0, stream>>>(seqb, v2eb, out);
}

// Round 10
// 389.342 us; speedup vs baseline: 1.3340x; 1.3340x over previous
//
#include <hip/hip_runtime.h>
#include <stdint.h>

#define N_NODES   120000
#define EM        128
#define N_EDGES_C 1920000
#define BSZ       1024
#define SL        10
#define N_GATHER  (BSZ*SL + BSZ)        // 11264
#define N_OUTCOL  (N_NODES - 1)         // 119999
#define NBLK_E    1875                  // 1875 * 1024 = 1920000 exactly
#define CHUNK_E   1024
#define NPANEL    938                   // 938*128 = 120064 >= 120000
#define NBLK_S    (NPANEL*8)            // 7504, divisible by 8

typedef __attribute__((ext_vector_type(8))) short bf16x8;
typedef __attribute__((ext_vector_type(4))) float f32x4;

#define GLOBAL_AS __attribute__((address_space(1)))
#define LDS_AS    __attribute__((address_space(3)))

__device__ inline void gload_lds16(const void* g, void* l) {
  __builtin_amdgcn_global_load_lds((const GLOBAL_AS unsigned int*)g,
                                   (LDS_AS unsigned int*)l, 16, 0, 0);
}

__device__ inline unsigned pk_bf16(float a, float b) {
  unsigned ua = __builtin_bit_cast(unsigned, a);
  ua += 0x7fffu + ((ua >> 16) & 1u);
  unsigned ub = __builtin_bit_cast(unsigned, b);
  ub += 0x7fffu + ((ub >> 16) & 1u);
  return (ua >> 16) | (ub & 0xffff0000u);
}

__device__ inline float bf2f(unsigned short u) {
  return __builtin_bit_cast(float, ((unsigned)u) << 16);
}

// ---- workspace layout (bytes) ----
#define MAP_OFF   0u          // int[120000]  node -> slot (-1 = unused)
#define CNT_OFF   480000u     // int[2]: slotCount (+pad to DEG_OFF)
#define DEG_OFF   480256u     // int[11264]
#define OFFS_OFF  525312u     // int[11264]
#define CUR_OFF   570368u     // int[11264]
#define AGG_OFF   615424u     // float[11264*128]
#define SORT_OFF  21742592u   // int[N_EDGES]
#define SB_OFF    35189760u   // ushort[1024*128] seq_emb bf16 (256 KB)
#define V2EB_OFF  37748736u   // ushort[120000*128] v2e bf16 (30.72 MB)

// ---------------- init: map=-1, counters+deg=0, one dispatch ----------------
__global__ __launch_bounds__(256) void k_init(int* __restrict__ ws_ints) {
  int t = blockIdx.x*256 + threadIdx.x;          // grid 513*256 = 131328 = 525312/4
  ws_ints[t] = (t < N_NODES) ? -1 : 0;
}

// ---------------- v2e f32 -> bf16 pre-pass ----------------
__global__ __launch_bounds__(256) void k_tobf16(const float* __restrict__ v2e,
    unsigned short* __restrict__ v2eb) {
  size_t base = ((size_t)blockIdx.x*256 + threadIdx.x) * 8;   // grid covers exactly
  float4 v0 = *(const float4*)(v2e + base);
  float4 v1 = *(const float4*)(v2e + base + 4);
  uint4 o;
  o.x = pk_bf16(v0.x, v0.y); o.y = pk_bf16(v0.z, v0.w);
  o.z = pk_bf16(v1.x, v1.y); o.w = pk_bf16(v1.z, v1.w);
  *(uint4*)(v2eb + base) = o;
}

// ---------------- slot assignment for gathered nodes ----------------
__global__ __launch_bounds__(256) void k_assign(const int* __restrict__ seq,
    const int* __restrict__ user, const int* __restrict__ item_num,
    int* __restrict__ map, int* __restrict__ slotCount) {
  int t = blockIdx.x*256 + threadIdx.x;
  int idx = (t < BSZ*SL) ? seq[t] : (user[t - BSZ*SL] + item_num[0]);
  int old = atomicCAS(map + idx, -1, -2);
  if (old == -1) {
    int slot = atomicAdd(slotCount, 1);
    atomicExch(map + idx, slot);
  }
}

// ---------------- pass 1: per-slot degree (spread atomics only) ----------------
__global__ __launch_bounds__(256) void k_count(const int* __restrict__ dst,
    const int* __restrict__ map, int* __restrict__ deg_i) {
  int beg = blockIdx.x * CHUNK_E;
  #pragma unroll
  for (int it = 0; it < CHUNK_E/256; ++it) {
    int e = beg + it*256 + threadIdx.x;
    int slot = map[dst[e]];
    if (slot >= 0) atomicAdd(deg_i + slot, 1);
  }
}

// ---------------- exclusive scan of per-slot degrees ----------------
__global__ __launch_bounds__(256) void k_scan(const int* __restrict__ deg_i,
    int* __restrict__ offs, int* __restrict__ cursor) {
  __shared__ int wsum[4];
  int tid = threadIdx.x;
  int lane = tid & 63, wv = tid >> 6;
  int carry = 0;
  for (int c = 0; c < N_GATHER/256; ++c) {
    int i = c*256 + tid;
    int v = deg_i[i];
    int s = v;
    #pragma unroll
    for (int o = 1; o < 64; o <<= 1) {
      int t = __shfl_up(s, o);
      if (lane >= o) s += t;
    }
    if (lane == 63) wsum[wv] = s;
    __syncthreads();
    int wbase = 0;
    #pragma unroll
    for (int q = 0; q < 4; ++q) if (q < wv) wbase += wsum[q];
    int tot = wsum[0] + wsum[1] + wsum[2] + wsum[3];
    int excl = s - v + wbase + carry;
    offs[i] = excl;
    cursor[i] = excl;
    carry += tot;
    __syncthreads();
  }
}

// ---------------- pass 2: direct scatter into per-slot buckets ----------------
__global__ __launch_bounds__(256) void k_place(const int* __restrict__ src,
    const int* __restrict__ dst, const int* __restrict__ map,
    int* __restrict__ cursor, int* __restrict__ sorted) {
  int beg = blockIdx.x * CHUNK_E;
  #pragma unroll
  for (int it = 0; it < CHUNK_E/256; ++it) {
    int e = beg + it*256 + threadIdx.x;
    int slot = map[dst[e]];
    if (slot >= 0) {
      int pos = atomicAdd(cursor + slot, 1);
      sorted[pos] = src[e];
    }
  }
}

// ---------------- per-slot neighbor sum, bf16 gather, f32 accum ----------------
__global__ __launch_bounds__(256) void k_reduce(const unsigned short* __restrict__ v2eb,
    const int* __restrict__ offs, const int* __restrict__ deg_i,
    const int* __restrict__ slotCount, const int* __restrict__ sorted,
    float* __restrict__ agg) {
  int nslots = slotCount[0];
  int g = (blockIdx.x*blockDim.x + threadIdx.x) >> 5;
  int lg = threadIdx.x & 31;
  int ngrp = (gridDim.x*blockDim.x) >> 5;
  for (int slot = g; slot < nslots; slot += ngrp) {
    int beg = offs[slot];
    int end = beg + deg_i[slot];
    float a0 = 0.f, a1 = 0.f, a2 = 0.f, a3 = 0.f;
    for (int e = beg; e < end; ++e) {
      int s = sorted[e];
      ushort4 v = *(const ushort4*)(v2eb + (size_t)s*EM + lg*4);
      a0 += bf2f(v.x); a1 += bf2f(v.y); a2 += bf2f(v.z); a3 += bf2f(v.w);
    }
    *(float4*)(agg + (size_t)slot*EM + lg*4) = make_float4(a0, a1, a2, a3);
  }
}

// ------- fused SAGE-embed + session attention: one block per batch row -------
__global__ __launch_bounds__(128) void k_fused(
    const int* __restrict__ seq, const int* __restrict__ user,
    const int* __restrict__ item_num, const int* __restrict__ map,
    const int* __restrict__ deg_i, const float* __restrict__ agg,
    const float* __restrict__ v2e,
    const float* __restrict__ W_self, const float* __restrict__ W_neigh,
    const float* __restrict__ sage_b,
    const int* __restrict__ pos_idx, const float* __restrict__ mask_in,
    const float* __restrict__ pos_emb,
    const float* __restrict__ w1, const float* __restrict__ w2,
    const float* __restrict__ glu1_w, const float* __restrict__ glu1_b,
    const float* __restrict__ glu2_w,
    const float* __restrict__ w3, const float* __restrict__ w4,
    const float* __restrict__ glu3_w, const float* __restrict__ glu3_b,
    const float* __restrict__ glu4_w,
    const float* __restrict__ sc_w, const float* __restrict__ sc_b,
    unsigned short* __restrict__ seqb) {
  __shared__ float xs[SL+1][EM], xa[SL+1][EM];   // xs becomes ne/ue after embed
  __shared__ float pe[SL][EM], r1[SL][EM], r2[SL][EM];
  __shared__ float hsS[EM], redA[EM];
  __shared__ float mls[SL], bl1[SL], bl2[SL];
  __shared__ float alphaS;
  int b = blockIdx.x, j = threadIdx.x;
  // ---- load 10 seq rows + 1 user row (v2e, agg/deg, pos_emb) ----
  #pragma unroll
  for (int l = 0; l < SL; ++l) {
    int idx = seq[b*SL + l];
    int slot = map[idx];
    float rd = 1.0f / fmaxf((float)deg_i[slot], 1.0f);
    xs[l][j] = v2e[(size_t)idx*EM + j];
    xa[l][j] = agg[(size_t)slot*EM + j] * rd;
    int p = pos_idx[b*SL + l];
    pe[l][j] = pos_emb[(size_t)p*EM + j];
  }
  {
    int idx = user[b] + item_num[0];
    int slot = map[idx];
    float rd = 1.0f / fmaxf((float)deg_i[slot], 1.0f);
    xs[SL][j] = v2e[(size_t)idx*EM + j];
    xa[SL][j] = agg[(size_t)slot*EM + j] * rd;
  }
  if (j < SL) mls[j] = mask_in[b*SL + j];
  __syncthreads();
  // ---- SAGE: h1 = relu(xs@W_self + xa@W_neigh + b); emb = 0.5*(h1+xs) ----
  float acc[SL+1];
  #pragma unroll
  for (int r = 0; r <= SL; ++r) acc[r] = 0.f;
  for (int k = 0; k < EM; ++k) {
    float a  = W_self[k*EM + j];
    float bb = W_neigh[k*EM + j];
    #pragma unroll
    for (int r = 0; r <= SL; ++r) acc[r] += xs[r][k]*a + xa[r][k]*bb;
  }
  float bias = sage_b[j];
  __syncthreads();                       // all reads of xs done before overwrite
  #pragma unroll
  for (int r = 0; r <= SL; ++r) {
    float h = fmaxf(acc[r] + bias, 0.0f);
    xs[r][j] = 0.5f * (h + xs[r][j]);    // xs now holds node/user embeds
  }
  __syncthreads();
  // ---- session attention (xs[0..9] = ne, xs[10] = ue) ----
  float s = 0.f, ms = 0.f;
  #pragma unroll
  for (int l = 0; l < SL; ++l) { s += mls[l]*xs[l][j]; ms += mls[l]; }
  hsS[j] = s / ms;
  float a1[SL], a2[SL];
  #pragma unroll
  for (int l = 0; l < SL; ++l) { a1[l] = 0.f; a2[l] = 0.f; }
  for (int k = 0; k < EM; ++k) {
    float wt  = w1[k*EM + j];
    float wb  = w1[(k+EM)*EM + j];
    float w3v = w3[k*EM + j];
    #pragma unroll
    for (int l = 0; l < SL; ++l) {
      a1[l] += pe[l][k]*wt + xs[l][k]*wb;
      a2[l] += xs[l][k]*w3v;
    }
  }
  #pragma unroll
  for (int l = 0; l < SL; ++l) { r1[l][j] = tanhf(a1[l]); r2[l][j] = tanhf(a2[l]); }
  __syncthreads();
  float g1[SL], g2[SL];
  #pragma unroll
  for (int l = 0; l < SL; ++l) { g1[l] = 0.f; g2[l] = 0.f; }
  float hsa = 0.f, uea = 0.f;
  for (int k = 0; k < EM; ++k) {
    float c1 = glu1_w[k*EM + j];
    float c2 = glu2_w[k*EM + j];
    float c3 = glu3_w[k*EM + j];
    float c4 = glu4_w[k*EM + j];
    hsa += hsS[k]*c2;
    uea += xs[SL][k]*c4;
    #pragma unroll
    for (int l = 0; l < SL; ++l) {
      g1[l] += r1[l][k]*c1;
      g2[l] += r2[l][k]*c3;
    }
  }
  float b1 = glu1_b[j], b3 = glu3_b[j];
  float w2v = w2[j], w4v = w4[j];
  __syncthreads();
  #pragma unroll
  for (int l = 0; l < SL; ++l) {
    float s1 = 1.f/(1.f + expf(-(g1[l] + b1 + hsa)));
    float s2 = 1.f/(1.f + expf(-(g2[l] + b3 + uea)));
    r1[l][j] = s1 * w2v;
    r2[l][j] = s2 * w4v;
  }
  __syncthreads();
  if (j < SL) {
    float t1 = 0.f, t2 = 0.f;
    for (int t = 0; t < EM; ++t) { t1 += r1[j][t]; t2 += r2[j][t]; }
    bl1[j] = t1 * mls[j];
    bl2[j] = t2 * mls[j];
  }
  __syncthreads();
  float sv = 0.f, su = 0.f;
  #pragma unroll
  for (int l = 0; l < SL; ++l) { sv += bl1[l]*xs[l][j]; su += bl2[l]*xs[l][j]; }
  redA[j] = sv*sc_w[j] + su*sc_w[EM + j];
  __syncthreads();
  if (j == 0) {
    float t = 0.f;
    for (int k = 0; k < EM; ++k) t += redA[k];
    alphaS = 1.f/(1.f + expf(-(t + sc_b[0])));
  }
  __syncthreads();
  float al = alphaS;
  float val = xs[SL][j] + al*sv + (1.f - al)*su;
  unsigned uv = __builtin_bit_cast(unsigned, val);
  uv += 0x7fffu + ((uv >> 16) & 1u);
  seqb[b*EM + j] = (unsigned short)(uv >> 16);
}

// ---------------- scores (round-5/8 version, best measured: ~200 us) ----------
__global__ __launch_bounds__(256, 3) void k_scores(
    const unsigned short* __restrict__ seqb,
    const unsigned short* __restrict__ v2eb, float* __restrict__ out) {
  __shared__ char Bs[32768];
  __shared__ float scr[4][16][68];     // per-wave transpose scratch (padded +4)
  int tid = threadIdx.x;
  int bid = blockIdx.x;
  // bijective XCD swizzle: 8 m-blocks of a panel land on the same XCD
  int lid = (bid & 7) * (NBLK_S/8) + (bid >> 3);
  int m0 = (lid & 7) * 128;
  int n0 = (lid >> 3) * 128;
  int w = tid >> 6, lane = tid & 63;
  // stage B tile (128 rows x 128 k, bf16) with inverse-swizzled source
  const char* v2eb_c = (const char*)v2eb;
  #pragma unroll
  for (int i = 0; i < 8; ++i) {
    int chunk = i*4 + w;
    int o = chunk*1024 + lane*16;            // linear LDS offset this lane fills
    int row = o >> 8;
    int c = o & 255;
    int rowg = n0 + 1 + row;
    if (rowg > N_OUTCOL) rowg = N_OUTCOL;    // clamp; junk cols are masked at store
    const void* src = v2eb_c + (size_t)rowg*256 + (c ^ ((row & 7) << 4));
    gload_lds16(src, Bs + chunk*1024);
  }
  asm volatile("s_waitcnt vmcnt(0)");
  __syncthreads();

  int wm = w >> 1, wn = w & 1;
  int lr = lane & 15, lg = lane >> 4;
  f32x4 acc[4][4];
  #pragma unroll
  for (int mi = 0; mi < 4; ++mi)
    #pragma unroll
    for (int ni = 0; ni < 4; ++ni)
      acc[mi][ni] = 0.f;
  #pragma unroll
  for (int ks = 0; ks < 4; ++ks) {
    bf16x8 a[4], bfr[4];
    #pragma unroll
    for (int mi = 0; mi < 4; ++mi)
      a[mi] = *(const bf16x8*)(seqb + (size_t)(m0 + wm*64 + mi*16 + lr)*EM + ks*32 + lg*8);
    #pragma unroll
    for (int ni = 0; ni < 4; ++ni) {
      int row = wn*64 + ni*16 + lr;
      int off = (row*256 + ks*64 + lg*16) ^ ((row & 7) << 4);
      bfr[ni] = *(const bf16x8*)(Bs + off);
    }
    #pragma unroll
    for (int mi = 0; mi < 4; ++mi)
      #pragma unroll
      for (int ni = 0; ni < 4; ++ni)
        acc[mi][ni] = __builtin_amdgcn_mfma_f32_16x16x32_bf16(a[mi], bfr[ni], acc[mi][ni], 0, 0, 0);
  }

  // ---- transpose epilogue: 4 chunks of 16 rows x 64 cols per wave ----
  float (*sw)[68] = scr[w];
  int nbase = n0 + wn*64;
  #pragma unroll
  for (int mi = 0; mi < 4; ++mi) {
    #pragma unroll
    for (int ni = 0; ni < 4; ++ni)
      #pragma unroll
      for (int r = 0; r < 4; ++r)
        sw[lg*4 + r][ni*16 + lr] = acc[mi][ni][r];
    asm volatile("s_waitcnt lgkmcnt(0)" ::: "memory");
    #pragma unroll
    for (int q = 0; q < 4; ++q) {
      int row16 = q*4 + lg;
      float4 v = *(const float4*)&sw[row16][lr*4];
      int m = m0 + wm*64 + mi*16 + row16;
      int nc = nbase + lr*4;
      size_t base = (size_t)m * N_OUTCOL + nc;
      if (nc + 3 < N_OUTCOL) {
        *(float4*)(out + base) = v;
      } else if (nc < N_OUTCOL) {
        float vv[4] = {v.x, v.y, v.z, v.w};
        #pragma unroll
        for (int t = 0; t < 4; ++t)
          if (nc + t < N_OUTCOL) out[base + t] = vv[t];
      }
    }
    asm volatile("s_waitcnt lgkmcnt(0)" ::: "memory");
  }
}

extern "C" void kernel_launch(void* const* d_in, const int* in_sizes, int n_in,
                              void* d_out, int out_size, void* d_ws, size_t ws_size,
                              hipStream_t stream) {
  const int*   src      = (const int*)d_in[0];
  const int*   dst      = (const int*)d_in[1];
  const int*   user     = (const int*)d_in[2];
  const int*   seq      = (const int*)d_in[3];
  const float* mask     = (const float*)d_in[4];
  const int*   pos_idx  = (const int*)d_in[6];
  const int*   item_num = (const int*)d_in[7];
  const float* v2e      = (const float*)d_in[8];
  const float* W_self   = (const float*)d_in[9];
  const float* W_neigh  = (const float*)d_in[10];
  const float* sage_b   = (const float*)d_in[11];
  const float* pos_emb  = (const float*)d_in[12];
  const float* w1       = (const float*)d_in[13];
  const float* w2       = (const float*)d_in[14];
  const float* glu1_w   = (const float*)d_in[15];
  const float* glu1_b   = (const float*)d_in[16];
  const float* glu2_w   = (const float*)d_in[17];
  const float* w3       = (const float*)d_in[18];
  const float* w4       = (const float*)d_in[19];
  const float* glu3_w   = (const float*)d_in[20];
  const float* glu3_b   = (const float*)d_in[21];
  const float* glu4_w   = (const float*)d_in[22];
  const float* sc_w     = (const float*)d_in[23];
  const float* sc_b     = (const float*)d_in[24];
  float* out = (float*)d_out;
  char*  ws  = (char*)d_ws;

  int*   map       = (int*)(ws + MAP_OFF);
  int*   slotCount = (int*)(ws + CNT_OFF);
  int*   deg_i     = (int*)(ws + DEG_OFF);
  int*   offs      = (int*)(ws + OFFS_OFF);
  int*   cursor    = (int*)(ws + CUR_OFF);
  float* agg       = (float*)(ws + AGG_OFF);
  int*   sorted    = (int*)(ws + SORT_OFF);
  unsigned short* seqb  = (unsigned short*)(ws + SB_OFF);
  unsigned short* v2eb  = (unsigned short*)(ws + V2EB_OFF);

  k_init<<<513, 256, 0, stream>>>((int*)ws);          // map=-1, counters+deg=0
  k_tobf16<<<7500, 256, 0, stream>>>(v2e, v2eb);      // 15.36M elems / 8
  k_assign<<<N_GATHER/256, 256, 0, stream>>>(seq, user, item_num, map, slotCount);
  k_count<<<NBLK_E, 256, 0, stream>>>(dst, map, deg_i);
  k_scan<<<1, 256, 0, stream>>>(deg_i, offs, cursor);
  k_place<<<NBLK_E, 256, 0, stream>>>(src, dst, map, cursor, sorted);
  k_reduce<<<1408, 256, 0, stream>>>(v2eb, offs, deg_i, slotCount, sorted, agg);
  k_fused<<<BSZ, 128, 0, stream>>>(seq, user, item_num, map, deg_i, agg, v2e,
      W_self, W_neigh, sage_b, pos_idx, mask, pos_emb,
      w1, w2, glu1_w, glu1_b, glu2_w, w3, w4, glu3_w, glu3_b, glu4_w, sc_w, sc_b, seqb);
  k_scores<<<NBLK_S, 256, 0, stream>>>(seqb, v2eb, out);
}